// Round 4
// baseline (228.953 us; speedup 1.0000x reference)
//
#include <hip/hip_runtime.h>

#define FFT_N 4096
#define NT    256
// 3-term skew (round-2 measured: 3.1e6 conflict cycles, ~10x better than 2-term)
#define SK(i) ((i) + ((i) >> 4) + 2 * ((i) >> 8))

typedef float cplx __attribute__((ext_vector_type(2)));  // (re, im)

__device__ __forceinline__ cplx mkc(float re, float im) { cplx c; c.x = re; c.y = im; return c; }
// i*b and -i*b (swap + single-lane negate; backend folds into op_sel/neg where possible)
__device__ __forceinline__ cplx ixc(cplx b)  { return mkc(-b.y, b.x); }
__device__ __forceinline__ cplx nixc(cplx b) { return mkc(b.y, -b.x); }

// complex multiply via packed ops: broadcast a.x, a.y; 2 packed mul/fma + swap
__device__ __forceinline__ cplx cmul(cplx a, cplx b) {
    cplx are = mkc(a.x, a.x);
    cplx aim = mkc(a.y, a.y);
    cplx bsw = mkc(-b.y, b.x);
    return are * b + aim * bsw;   // (a.x*b.x - a.y*b.y, a.x*b.y + a.y*b.x)
}
// a * conj(b)
__device__ __forceinline__ cplx cmulc(cplx a, cplx b) {
    cplx are = mkc(a.x, a.x);
    cplx aim = mkc(a.y, a.y);
    return are * mkc(b.x, -b.y) + aim * mkc(b.y, b.x);  // (a.x*b.x + a.y*b.y, a.y*b.x - a.x*b.y)
}

// In-register 16-point DFT, natural order in/out. SGN=-1 fwd, +1 inv (unnormalized).
template <int SGN>
__device__ __forceinline__ void dft16(cplx* x) {
    const float S = (float)SGN;
    const float C1 = 0.92387953251128675613f;   // cos(pi/8)
    const float S1 = 0.38268343236508977173f;   // sin(pi/8)
    const float R2 = 0.70710678118654752440f;   // sqrt(2)/2
    cplx B[16];  // B[n0*4 + r]
#pragma unroll
    for (int n0 = 0; n0 < 4; ++n0) {
        cplx x0 = x[n0], x1 = x[n0 + 4], x2 = x[n0 + 8], x3 = x[n0 + 12];
        cplx t0 = x0 + x2, t1 = x0 - x2;
        cplx t2 = x1 + x3, t3 = x1 - x3;
        cplx it3 = (SGN < 0) ? nixc(t3) : ixc(t3);   // S*i*t3
        B[n0 * 4 + 0] = t0 + t2;
        B[n0 * 4 + 2] = t0 - t2;
        B[n0 * 4 + 1] = t1 + it3;
        B[n0 * 4 + 3] = t1 - it3;
    }
    // inter-layer twiddles W16^(S*n0*r), constants; (2,2) is w4 = S*i (swap-neg)
    const cplx w1 = mkc(C1, S * S1), w2 = mkc(R2, S * R2), w3 = mkc(S1, S * C1);
    const cplx w6 = mkc(-R2, S * R2), w9 = mkc(-C1, -S * S1);
    B[5]  = cmul(B[5],  w1);
    B[6]  = cmul(B[6],  w2);
    B[7]  = cmul(B[7],  w3);
    B[9]  = cmul(B[9],  w2);
    B[10] = (SGN < 0) ? nixc(B[10]) : ixc(B[10]);
    B[11] = cmul(B[11], w6);
    B[13] = cmul(B[13], w3);
    B[14] = cmul(B[14], w6);
    B[15] = cmul(B[15], w9);
#pragma unroll
    for (int r = 0; r < 4; ++r) {
        cplx b0 = B[r], b1 = B[4 + r], b2 = B[8 + r], b3 = B[12 + r];
        cplx t0 = b0 + b2, t1 = b0 - b2;
        cplx t2 = b1 + b3, t3 = b1 - b3;
        cplx it3 = (SGN < 0) ? nixc(t3) : ixc(t3);
        x[r]      = t0 + t2;
        x[r + 8]  = t0 - t2;
        x[r + 4]  = t1 + it3;
        x[r + 12] = t1 - it3;
    }
}

// apply x[r] *= w1^r for r=1..15 (chained; register-light)
__device__ __forceinline__ void twiddle_apply(cplx* x, cplx w1) {
    cplx w = w1;
    x[1] = cmul(x[1], w);
#pragma unroll
    for (int r = 2; r < 16; ++r) { w = cmul(w, w1); x[r] = cmul(x[r], w); }
}
// apply x[r] *= conj(w1^r)
__device__ __forceinline__ void twiddle_apply_conj(cplx* x, cplx w1) {
    cplx w = w1;
    x[1] = cmulc(x[1], w);
#pragma unroll
    for (int r = 2; r < 16; ++r) { w = cmul(w, w1); x[r] = cmulc(x[r], w); }
}

__global__ __launch_bounds__(NT, 4) void circconv4096_kernel(
    const float* __restrict__ A, const float* __restrict__ Bv,
    float* __restrict__ O)
{
    __shared__ cplx Z[4381];  // SK(4095)+1 = 35 KB -> 4 blocks/CU
    const int t = threadIdx.x;
    const size_t row = blockIdx.x;
    const float* a = A + row * FFT_N;
    const float* b = Bv + row * FFT_N;
    float* o = O + row * FFT_N;

    cplx x[16];
    cplx w1t, w1j;  // stage-1/2 base twiddles, conj-reused in stages 5/4

    // ---- step 1: coalesced load + fwd radix-16 stage (stride 256) ----
#pragma unroll
    for (int q = 0; q < 16; ++q) {
        int g = t + NT * q;
        x[q] = mkc(a[g], b[g]);   // z = a + i*b
    }
    dft16<-1>(x);
    {
        float sn, cs;
        __sincosf(-6.28318530717958647692f * (float)t / 4096.0f, &sn, &cs);
        w1t = mkc(cs, sn);
    }
    twiddle_apply(x, w1t);
#pragma unroll
    for (int r = 0; r < 16; ++r) Z[SK(t + NT * r)] = x[r];
    __syncthreads();

    // ---- step 2: fwd radix-16 stage (stride 16) ----
    const int base = ((t >> 4) << 8) + (t & 15);
    {
#pragma unroll
        for (int q = 0; q < 16; ++q) x[q] = Z[SK(base + 16 * q)];
        dft16<-1>(x);
        float sn, cs;
        __sincosf(-6.28318530717958647692f * (float)(t & 15) / 256.0f, &sn, &cs);
        w1j = mkc(cs, sn);
        twiddle_apply(x, w1j);
#pragma unroll
        for (int r = 0; r < 16; ++r) Z[SK(base + 16 * r)] = x[r];
    }
    __syncthreads();

    // ---- step 3: fwd contiguous stage + pointwise square + inv contiguous stage ----
    {
        const int b3 = t * 16;
#pragma unroll
        for (int q = 0; q < 16; ++q) x[q] = Z[SK(b3 + q)];
        dft16<-1>(x);
#pragma unroll
        for (int r = 0; r < 16; ++r) x[r] = cmul(x[r], x[r]);  // Z^2
        dft16<1>(x);
#pragma unroll
        for (int q = 0; q < 16; ++q) Z[SK(b3 + q)] = x[q];
    }
    __syncthreads();

    // ---- step 4: inv radix-16 stage (stride 16): conj twiddle, then inverse dft ----
    {
#pragma unroll
        for (int r = 0; r < 16; ++r) x[r] = Z[SK(base + 16 * r)];
        twiddle_apply_conj(x, w1j);
        dft16<1>(x);
#pragma unroll
        for (int q = 0; q < 16; ++q) Z[SK(base + 16 * q)] = x[q];
    }
    __syncthreads();

    // ---- step 5: inv radix-16 stage (stride 256) + coalesced store ----
    {
#pragma unroll
        for (int r = 0; r < 16; ++r) x[r] = Z[SK(t + NT * r)];
        twiddle_apply_conj(x, w1t);
        dft16<1>(x);
        // three unnormalized inverse dft16s = x4096; imag-extraction trick = /2
        const float scale = 1.0f / 8192.0f;
#pragma unroll
        for (int q = 0; q < 16; ++q) o[t + NT * q] = x[q].y * scale;
    }
}

extern "C" void kernel_launch(void* const* d_in, const int* in_sizes, int n_in,
                              void* d_out, int out_size, void* d_ws, size_t ws_size,
                              hipStream_t stream) {
    const float* a = (const float*)d_in[0];
    const float* b = (const float*)d_in[1];
    float* out = (float*)d_out;
    const int B = in_sizes[0] / FFT_N;  // 8192 rows
    circconv4096_kernel<<<B, NT, 0, stream>>>(a, b, out);
}

// Round 5
// 162.724 us; speedup vs baseline: 1.4070x; 1.4070x over previous
//
#include <hip/hip_runtime.h>

#define FFT_N 4096
#define NT    256
// additive skew: affine in all access strides (1/16/256) -> one base + imm offsets
#define SK(i) ((i) + ((i) >> 4) + 2 * ((i) >> 8))

__device__ __forceinline__ float2 cadd(float2 a, float2 b) { return make_float2(a.x + b.x, a.y + b.y); }
__device__ __forceinline__ float2 csub(float2 a, float2 b) { return make_float2(a.x - b.x, a.y - b.y); }
__device__ __forceinline__ float2 cmul(float2 a, float2 b) {
    return make_float2(a.x * b.x - a.y * b.y, a.x * b.y + a.y * b.x);
}
__device__ __forceinline__ float2 cmulc(float2 a, float2 b) {  // a * conj(b)
    return make_float2(a.x * b.x + a.y * b.y, a.y * b.x - a.x * b.y);
}

// In-register 16-point DFT, natural order in/out. SGN=-1 fwd, +1 inv (unnormalized).
template <int SGN>
__device__ __forceinline__ void dft16(float2* x) {
    const float S = (float)SGN;
    const float C1 = 0.92387953251128675613f;   // cos(pi/8)
    const float S1 = 0.38268343236508977173f;   // sin(pi/8)
    const float R2 = 0.70710678118654752440f;   // sqrt(2)/2
    float2 B[16];  // B[n0*4 + r]
#pragma unroll
    for (int n0 = 0; n0 < 4; ++n0) {
        float2 x0 = x[n0], x1 = x[n0 + 4], x2 = x[n0 + 8], x3 = x[n0 + 12];
        float2 t0 = cadd(x0, x2), t1 = csub(x0, x2);
        float2 t2 = cadd(x1, x3), t3 = csub(x1, x3);
        float2 it3 = make_float2(-S * t3.y, S * t3.x);  // S*i*t3
        B[n0 * 4 + 0] = cadd(t0, t2);
        B[n0 * 4 + 2] = csub(t0, t2);
        B[n0 * 4 + 1] = cadd(t1, it3);
        B[n0 * 4 + 3] = csub(t1, it3);
    }
    // inter-layer twiddles W16^(S*n0*r), constants; (2,2) is w4 = S*i
    const float2 w1 = make_float2(C1, S * S1), w2 = make_float2(R2, S * R2), w3 = make_float2(S1, S * C1);
    const float2 w6 = make_float2(-R2, S * R2), w9 = make_float2(-C1, -S * S1);
    B[5]  = cmul(B[5],  w1);
    B[6]  = cmul(B[6],  w2);
    B[7]  = cmul(B[7],  w3);
    B[9]  = cmul(B[9],  w2);
    {   float2 v = B[10]; B[10] = make_float2(-S * v.y, S * v.x); }
    B[11] = cmul(B[11], w6);
    B[13] = cmul(B[13], w3);
    B[14] = cmul(B[14], w6);
    B[15] = cmul(B[15], w9);
#pragma unroll
    for (int r = 0; r < 4; ++r) {
        float2 b0 = B[r], b1 = B[4 + r], b2 = B[8 + r], b3 = B[12 + r];
        float2 t0 = cadd(b0, b2), t1 = csub(b0, b2);
        float2 t2 = cadd(b1, b3), t3 = csub(b1, b3);
        float2 it3 = make_float2(-S * t3.y, S * t3.x);
        x[r]      = cadd(t0, t2);
        x[r + 8]  = csub(t0, t2);
        x[r + 4]  = cadd(t1, it3);
        x[r + 12] = csub(t1, it3);
    }
}

// d_ws layout: twA[4096] = W4096^(t*r) at [r*256+t]; twB[256] = W256^(j*r) at [r*16+j]
__global__ void twiddle_init(float2* __restrict__ twA, float2* __restrict__ twB) {
    int m = blockIdx.x * NT + threadIdx.x;   // 0..4351
    float s, c;
    if (m < 4096) {
        int r = m >> 8, t = m & 255;
        sincosf(-6.28318530717958647692f * (float)(t * r) / 4096.0f, &s, &c);
        twA[m] = make_float2(c, s);
    } else {
        int k = m - 4096;                    // k = r*16 + j
        int r = k >> 4, j = k & 15;
        sincosf(-6.28318530717958647692f * (float)(j * r) / 256.0f, &s, &c);
        twB[k] = make_float2(c, s);
    }
}

__global__ __launch_bounds__(NT, 4) void circconv4096_kernel(
    const float* __restrict__ A, const float* __restrict__ Bv,
    float* __restrict__ O,
    const float2* __restrict__ twA, const float2* __restrict__ twB)
{
    __shared__ float2 Z[4381];  // SK(4095)+1 = 35 KB -> 4 blocks/CU
    const int t = threadIdx.x;
    const size_t row = blockIdx.x;
    const float* a = A + row * FFT_N;
    const float* b = Bv + row * FFT_N;
    float* o = O + row * FFT_N;

    float2 x[16];

    // ---- step 1: coalesced load + fwd radix-16 stage (stride 256) ----
#pragma unroll
    for (int q = 0; q < 16; ++q) {
        int g = t + NT * q;
        x[q] = make_float2(a[g], b[g]);   // z = a + i*b
    }
    dft16<-1>(x);
#pragma unroll
    for (int r = 1; r < 16; ++r) x[r] = cmul(x[r], twA[r * 256 + t]);
#pragma unroll
    for (int r = 0; r < 16; ++r) Z[SK(t + NT * r)] = x[r];
    __syncthreads();

    // ---- step 2: fwd radix-16 stage (stride 16) ----
    const int base = ((t >> 4) << 8) + (t & 15);
    const int j = t & 15;
    {
#pragma unroll
        for (int q = 0; q < 16; ++q) x[q] = Z[SK(base + 16 * q)];
        dft16<-1>(x);
#pragma unroll
        for (int r = 1; r < 16; ++r) x[r] = cmul(x[r], twB[r * 16 + j]);
#pragma unroll
        for (int r = 0; r < 16; ++r) Z[SK(base + 16 * r)] = x[r];
    }
    __syncthreads();

    // ---- step 3: fwd contiguous stage + pointwise square + inv contiguous stage ----
    {
        const int b3 = t * 16;
#pragma unroll
        for (int q = 0; q < 16; ++q) x[q] = Z[SK(b3 + q)];
        dft16<-1>(x);
#pragma unroll
        for (int r = 0; r < 16; ++r) {
            float2 z = x[r];
            x[r] = make_float2(z.x * z.x - z.y * z.y, 2.0f * z.x * z.y);  // Z^2
        }
        dft16<1>(x);
#pragma unroll
        for (int q = 0; q < 16; ++q) Z[SK(b3 + q)] = x[q];
    }
    __syncthreads();

    // ---- step 4: inv radix-16 stage (stride 16): conj twiddle, then inverse dft ----
    {
#pragma unroll
        for (int r = 0; r < 16; ++r) x[r] = Z[SK(base + 16 * r)];
#pragma unroll
        for (int r = 1; r < 16; ++r) x[r] = cmulc(x[r], twB[r * 16 + j]);
        dft16<1>(x);
#pragma unroll
        for (int q = 0; q < 16; ++q) Z[SK(base + 16 * q)] = x[q];
    }
    __syncthreads();

    // ---- step 5: inv radix-16 stage (stride 256) + coalesced store ----
    {
#pragma unroll
        for (int r = 0; r < 16; ++r) x[r] = Z[SK(t + NT * r)];
#pragma unroll
        for (int r = 1; r < 16; ++r) x[r] = cmulc(x[r], twA[r * 256 + t]);
        dft16<1>(x);
        // three unnormalized inverse dft16s = x4096; imag-extraction trick = /2
        const float scale = 1.0f / 8192.0f;
#pragma unroll
        for (int q = 0; q < 16; ++q) o[t + NT * q] = x[q].y * scale;
    }
}

extern "C" void kernel_launch(void* const* d_in, const int* in_sizes, int n_in,
                              void* d_out, int out_size, void* d_ws, size_t ws_size,
                              hipStream_t stream) {
    const float* a = (const float*)d_in[0];
    const float* b = (const float*)d_in[1];
    float* out = (float*)d_out;
    float2* twA = (float2*)d_ws;          // 4096 float2 = 32 KB
    float2* twB = twA + 4096;             // 256 float2 = 2 KB
    const int B = in_sizes[0] / FFT_N;    // 8192 rows

    twiddle_init<<<17, NT, 0, stream>>>(twA, twB);   // 4352 threads
    circconv4096_kernel<<<B, NT, 0, stream>>>(a, b, out, twA, twB);
}